// Round 11
// baseline (571.796 us; speedup 1.0000x reference)
//
#include <hip/hip_runtime.h>
#include <hip/hip_fp16.h>

// DeepfakeGNN: 2-layer GCN (self-loops, symmetric norm) + mean-pool + linear.
// Round 10 -> 11: INSTRUMENTED ROUND. Per-kernel budget no longer reconciles
// with total (models say ~105us, measured 218us) and all kernels sit below the
// 43us fill-kernel top-5 cutoff. This round rep-loops the 4 main kernels
// (gemm1 x8, gemm2 x12, gather1 x4, gather2 x4 — idempotent; asm memory
// clobber defeats cross-rep CSE) to push them into the top-5 WITH counters.
// True cost = dur/rep. Everything else byte-identical to R10. dur sacrificial.

#define TPB 256
#define CAP 64  // slots per node; max degree ~40 for this input

#define REP_GEMM1 8
#define REP_GEMM2 12
#define REP_GATHER 4

typedef short bfrag __attribute__((ext_vector_type(8)));   // 8 bf16 (4 VGPRs)
typedef float f32x4 __attribute__((ext_vector_type(4)));   // MFMA acc

__device__ __forceinline__ unsigned short f2bf(float f) {
  unsigned u = __float_as_uint(f);
  unsigned r = u + 0x7FFFu + ((u >> 16) & 1u);  // RNE
  return (unsigned short)(r >> 16);
}
__device__ __forceinline__ float bf2f(unsigned short b) {
  return __uint_as_float(((unsigned)b) << 16);
}

__global__ __launch_bounds__(TPB) void k_zero_i32(int* p, int n) {
  int i = blockIdx.x * TPB + threadIdx.x;
  if (i < n) p[i] = 0;
}

// pairw[d*CAP + slot] = src<<16 ; cursor[d] ends = in-degree (excl self loop)
__global__ __launch_bounds__(TPB) void k_scatter(const int* __restrict__ src,
                                                 const int* __restrict__ dst,
                                                 int* __restrict__ cursor,
                                                 unsigned* __restrict__ pairw, int E) {
  int e = blockIdx.x * TPB + threadIdx.x;
  if (e >= E) return;
  int s = src[e], d = dst[e];
  int pos = d * CAP + atomicAdd(&cursor[d], 1);
  pairw[pos] = ((unsigned)s) << 16;
}

// OR fp16(dinv[src]*dinv[dst]) into low 16 bits; dinv = rsqrt(cnt+1) on the fly
__global__ __launch_bounds__(TPB) void k_coef(const int* __restrict__ cnt,
                                              unsigned* __restrict__ pairw, int N) {
  int t = blockIdx.x * TPB + threadIdx.x;
  int node = t >> 6;
  if (node >= N) return;
  int slot = t & 63;
  if (slot >= cnt[node]) return;
  int pos = node * CAP + slot;
  unsigned u = pairw[pos];
  int j = (int)(u >> 16);
  float di = rsqrtf((float)(cnt[node] + 1));
  float dj = rsqrtf((float)(cnt[j] + 1));
  __half h = __float2half(di * dj);
  pairw[pos] = u | (unsigned)(*(unsigned short*)&h);
}

// pack W1 and W2 fp32 -> split bf16 fragment layout [K/32][256][32], one launch
__global__ __launch_bounds__(TPB) void k_packW(const float* __restrict__ W1,
                                               unsigned short* __restrict__ B1h,
                                               unsigned short* __restrict__ B1l,
                                               int K1,
                                               const float* __restrict__ W2,
                                               unsigned short* __restrict__ B2h,
                                               unsigned short* __restrict__ B2l,
                                               int K2) {
  int t = blockIdx.x * TPB + threadIdx.x;
  const float* W = W1;
  unsigned short* Bh = B1h;
  unsigned short* Bl = B1l;
  if (t >= K1 * 256) {
    t -= K1 * 256;
    if (t >= K2 * 256) return;
    W = W2; Bh = B2h; Bl = B2l;
  }
  int n = t & 255, k = t >> 8;
  float v = W[(size_t)k * 256 + n];
  unsigned short h = f2bf(v);
  unsigned short l = f2bf(v - bf2f(h));
  size_t o = ((size_t)(k >> 5) * 256 + n) * 32 + (k & 31);
  Bh[o] = h;
  Bl[o] = l;
}

// ---------- split-bf16 MFMA GEMM, C[M,256] = A[M,K] @ W[K,256], C in fp16 ----
// 256 thr = 4 waves; tile 64 rows x 256 cols; BK=64 per barrier pair.
#define LDSTR 72  // 64 + 8 pad (2-way LDS aliasing only = free)

__device__ __forceinline__ void gemm_core(const unsigned short* __restrict__ Bph,
                                          const unsigned short* __restrict__ Bpl,
                                          __half* __restrict__ C, int M, int K,
                                          int bm, unsigned short (*AsH)[LDSTR],
                                          unsigned short (*AsL)[LDSTR],
                                          const float* A_f32,
                                          const __half* A_f16) {
  const int tid = threadIdx.x;
  const int w = tid >> 6;
  const int lane = tid & 63;
  const int q = lane >> 4;        // quad 0..3
  const int nin = lane & 15;
  const int r  = tid >> 2;        // 0..63  staging row
  const int cb = (tid & 3) << 4;  // 0,16,32,48 staging k-offset (16 elems/thr)
  const int row = bm + r;
  const bool rok = row < M;

  size_t bbase[4];
#pragma unroll
  for (int nt = 0; nt < 4; ++nt)
    bbase[nt] = ((size_t)(w * 64 + nt * 16 + nin)) * 32 + q * 8;

  f32x4 acc[4][4];
#pragma unroll
  for (int mt = 0; mt < 4; ++mt)
#pragma unroll
    for (int nt = 0; nt < 4; ++nt) acc[mt][nt] = (f32x4){0.f, 0.f, 0.f, 0.f};

  for (int kb = 0; kb < K; kb += 64) {
    // stage A: 16 k-elems per thread, convert to split bf16
    float vv[16];
    if (A_f32) {
      float4 v0 = make_float4(0.f, 0.f, 0.f, 0.f), v1 = v0, v2 = v0, v3 = v0;
      if (rok) {
        const float* Ap = A_f32 + (size_t)row * K + kb + cb;
        v0 = *(const float4*)(Ap);
        v1 = *(const float4*)(Ap + 4);
        v2 = *(const float4*)(Ap + 8);
        v3 = *(const float4*)(Ap + 12);
      }
      *(float4*)&vv[0] = v0; *(float4*)&vv[4] = v1;
      *(float4*)&vv[8] = v2; *(float4*)&vv[12] = v3;
    } else {
      uint4 u0 = make_uint4(0, 0, 0, 0), u1 = u0;
      if (rok) {
        const __half* Ap = A_f16 + (size_t)row * K + kb + cb;
        u0 = *(const uint4*)(Ap);
        u1 = *(const uint4*)(Ap + 8);
      }
      __half hh[16];
      *(uint4*)&hh[0] = u0; *(uint4*)&hh[8] = u1;
#pragma unroll
      for (int j = 0; j < 16; ++j) vv[j] = __half2float(hh[j]);
    }
    unsigned short h16[16], l16[16];
#pragma unroll
    for (int j = 0; j < 16; ++j) {
      h16[j] = f2bf(vv[j]);
      l16[j] = f2bf(vv[j] - bf2f(h16[j]));   // exact for fp16 inputs
    }
    __syncthreads();
    *(uint4*)&AsH[r][cb]     = *(uint4*)&h16[0];
    *(uint4*)&AsH[r][cb + 8] = *(uint4*)&h16[8];
    *(uint4*)&AsL[r][cb]     = *(uint4*)&l16[0];
    *(uint4*)&AsL[r][cb + 8] = *(uint4*)&l16[8];
    __syncthreads();

#pragma unroll
    for (int s = 0; s < 2; ++s) {
      const size_t koff = (size_t)((kb >> 5) + s) * 256 * 32;
      bfrag bh[4], bl[4];
#pragma unroll
      for (int nt = 0; nt < 4; ++nt) {
        bh[nt] = *(const bfrag*)(Bph + koff + bbase[nt]);
        bl[nt] = *(const bfrag*)(Bpl + koff + bbase[nt]);
      }
      bfrag ah[4], al[4];
#pragma unroll
      for (int mt = 0; mt < 4; ++mt) {
        ah[mt] = *(const bfrag*)&AsH[mt * 16 + nin][s * 32 + q * 8];
        al[mt] = *(const bfrag*)&AsL[mt * 16 + nin][s * 32 + q * 8];
      }
#pragma unroll
      for (int mt = 0; mt < 4; ++mt)
#pragma unroll
        for (int nt = 0; nt < 4; ++nt) {
          acc[mt][nt] = __builtin_amdgcn_mfma_f32_16x16x32_bf16(ah[mt], bh[nt], acc[mt][nt], 0, 0, 0);
          acc[mt][nt] = __builtin_amdgcn_mfma_f32_16x16x32_bf16(ah[mt], bl[nt], acc[mt][nt], 0, 0, 0);
          acc[mt][nt] = __builtin_amdgcn_mfma_f32_16x16x32_bf16(al[mt], bh[nt], acc[mt][nt], 0, 0, 0);
        }
    }
  }

  // C/D layout: col = lane&15, row = quad*4 + reg ; store fp16
#pragma unroll
  for (int mt = 0; mt < 4; ++mt) {
    int rb = bm + mt * 16 + q * 4;
#pragma unroll
    for (int reg = 0; reg < 4; ++reg) {
      int rr = rb + reg;
      if (rr < M) {
#pragma unroll
        for (int nt = 0; nt < 4; ++nt)
          C[(size_t)rr * 256 + w * 64 + nt * 16 + nin] = __float2half(acc[mt][nt][reg]);
      }
    }
  }
}

__global__ __launch_bounds__(TPB) void k_gemm1(const float* __restrict__ A,
                                               const unsigned short* __restrict__ Bph,
                                               const unsigned short* __restrict__ Bpl,
                                               __half* __restrict__ C, int M, int K) {
  __shared__ unsigned short AsH[64][LDSTR];
  __shared__ unsigned short AsL[64][LDSTR];
  for (int rep = 0; rep < REP_GEMM1; ++rep) {          // instrumentation
    gemm_core(Bph, Bpl, C, M, K, blockIdx.x * 64, AsH, AsL, A, nullptr);
    __syncthreads();
    asm volatile("" ::: "memory");
  }
}

__global__ __launch_bounds__(TPB) void k_gemm2(const __half* __restrict__ A,
                                               const unsigned short* __restrict__ Bph,
                                               const unsigned short* __restrict__ Bpl,
                                               __half* __restrict__ C, int M, int K) {
  __shared__ unsigned short AsH[64][LDSTR];
  __shared__ unsigned short AsL[64][LDSTR];
  for (int rep = 0; rep < REP_GEMM2; ++rep) {          // instrumentation
    gemm_core(Bph, Bpl, C, M, K, blockIdx.x * 64, AsH, AsL, nullptr, A);
    __syncthreads();
    asm volatile("" ::: "memory");
  }
}

// ---------- chunked gathers: 2 chunks x 128 cols; chunk = blockIdx&1 ----------
__device__ __forceinline__ float2 gather_row2(const __half2* __restrict__ xh2,
                                              const unsigned* __restrict__ pairw,
                                              int node, int deg, int c2) {
  float ax = 0.f, ay = 0.f;
  int base = node * CAP;
  int k = 0;
  for (; k + 7 < deg; k += 8) {
#pragma unroll
    for (int u = 0; u < 8; ++u) {
      unsigned uu = pairw[base + k + u];
      const __half2* rp = xh2 + ((size_t)(uu >> 16) << 7);  // row*128 half2
      unsigned short cb16 = (unsigned short)(uu & 0xFFFFu);
      float coef = __half2float(*(__half*)&cb16);
      float2 v = __half22float2(rp[c2]);
      ax = fmaf(coef, v.x, ax);
      ay = fmaf(coef, v.y, ay);
    }
  }
  for (; k < deg; ++k) {
    unsigned uu = pairw[base + k];
    const __half2* rp = xh2 + ((size_t)(uu >> 16) << 7);
    unsigned short cb16 = (unsigned short)(uu & 0xFFFFu);
    float coef = __half2float(*(__half*)&cb16);
    float2 v = __half22float2(rp[c2]);
    ax = fmaf(coef, v.x, ax);
    ay = fmaf(coef, v.y, ay);
  }
  return make_float2(ax, ay);
}

// layer 1: h1 = relu(agg + b1), stored fp16 (half2 store)
__global__ __launch_bounds__(TPB) void k_gather1(const __half2* __restrict__ xh2,
                                                 const int* __restrict__ cnt,
                                                 const unsigned* __restrict__ pairw,
                                                 const float* __restrict__ bias,
                                                 __half2* __restrict__ h1,
                                                 int N) {
  int b = blockIdx.x;
  int chunk = b & 1;
  int node = __builtin_amdgcn_readfirstlane((b >> 1) * 4 + (threadIdx.x >> 6));
  if (node >= N) return;
  int deg = __builtin_amdgcn_readfirstlane(cnt[node]);
  int c2 = chunk * 64 + (threadIdx.x & 63);    // half2 index within row
  for (int rep = 0; rep < REP_GATHER; ++rep) {         // instrumentation
    float2 acc = gather_row2(xh2, pairw, node, deg, c2);
    float di2 = 1.f / (float)(deg + 1);        // dinv^2 exactly
    float2 sv = __half22float2(xh2[(size_t)node * 128 + c2]);
    acc.x = fmaf(di2, sv.x, acc.x);
    acc.y = fmaf(di2, sv.y, acc.y);
    const float2 bb = *(const float2*)&bias[2 * c2];
    acc.x = fmaxf(acc.x + bb.x, 0.f);
    acc.y = fmaxf(acc.y + bb.y, 0.f);
    h1[(size_t)node * 128 + c2] = __floats2half2_rn(acc.x, acc.y);
    asm volatile("" ::: "memory");
  }
}

// layer 2 + pooling partial: pdot[chunk][node] = sum_c relu(agg+b2)[c]*wfc[c]
__global__ __launch_bounds__(TPB) void k_gather2(const __half2* __restrict__ xh2,
                                                 const int* __restrict__ cnt,
                                                 const unsigned* __restrict__ pairw,
                                                 const float* __restrict__ bias,
                                                 const float* __restrict__ wfc,
                                                 float* __restrict__ pdot, int N) {
  int b = blockIdx.x;
  int chunk = b & 1;
  int node = __builtin_amdgcn_readfirstlane((b >> 1) * 4 + (threadIdx.x >> 6));
  if (node >= N) return;
  int deg = __builtin_amdgcn_readfirstlane(cnt[node]);
  int lane = threadIdx.x & 63;
  int c2 = chunk * 64 + lane;
  for (int rep = 0; rep < REP_GATHER; ++rep) {         // instrumentation
    float2 acc = gather_row2(xh2, pairw, node, deg, c2);
    float di2 = 1.f / (float)(deg + 1);
    float2 sv = __half22float2(xh2[(size_t)node * 128 + c2]);
    acc.x = fmaf(di2, sv.x, acc.x);
    acc.y = fmaf(di2, sv.y, acc.y);
    const float2 bb = *(const float2*)&bias[2 * c2];
    const float2 ff = *(const float2*)&wfc[2 * c2];
    float s = fmaxf(acc.x + bb.x, 0.f) * ff.x + fmaxf(acc.y + bb.y, 0.f) * ff.y;
#pragma unroll
    for (int off = 32; off > 0; off >>= 1) s += __shfl_down(s, off);
    if (lane == 0) pdot[(size_t)chunk * N + node] = s;
    asm volatile("" ::: "memory");
  }
}

// one block per group: binary-search [start,end) in sorted batch, reduce pdot.
__global__ __launch_bounds__(TPB) void k_pool(const float* __restrict__ pdot,
                                              const int* __restrict__ batch,
                                              const float* __restrict__ bfc,
                                              float* __restrict__ out, int N) {
  int g = blockIdx.x;
  int lo = 0, hi = N;
  while (lo < hi) { int mid = (lo + hi) >> 1; if (batch[mid] < g) lo = mid + 1; else hi = mid; }
  int start = lo;
  hi = N;
  while (lo < hi) { int mid = (lo + hi) >> 1; if (batch[mid] < g + 1) lo = mid + 1; else hi = mid; }
  int end = lo;

  float s = 0.f;
  for (int i = start + threadIdx.x; i < end; i += TPB)
    s += pdot[i] + pdot[(size_t)N + i];
  __shared__ float red[4];
  int lane = threadIdx.x & 63, wave = threadIdx.x >> 6;
#pragma unroll
  for (int off = 32; off > 0; off >>= 1) s += __shfl_down(s, off);
  if (lane == 0) red[wave] = s;
  __syncthreads();
  if (threadIdx.x == 0) {
    float tot = red[0] + red[1] + red[2] + red[3];
    float c = (float)(end - start);
    out[g] = tot / fmaxf(c, 1.f) + bfc[0];
  }
}

extern "C" void kernel_launch(void* const* d_in, const int* in_sizes, int n_in,
                              void* d_out, int out_size, void* d_ws, size_t ws_size,
                              hipStream_t stream) {
  const float* x    = (const float*)d_in[0];
  const int*   eidx = (const int*)d_in[1];
  const int*   batch= (const int*)d_in[2];
  const float* W1   = (const float*)d_in[3];
  const float* b1   = (const float*)d_in[4];
  const float* W2   = (const float*)d_in[5];
  const float* b2   = (const float*)d_in[6];
  const float* wfc  = (const float*)d_in[7];
  const float* bfc  = (const float*)d_in[8];
  float* out = (float*)d_out;

  const int N  = in_sizes[2];        // 20000
  const int E  = in_sizes[1] / 2;    // 320000
  const int K1 = in_sizes[0] / N;    // 512
  const int G  = out_size;           // 128

  const int* srcp = eidx;
  const int* dstp = eidx + E;

  auto al16 = [](size_t v) { return (v + 15) & ~(size_t)15; };
  char* ws = (char*)d_ws;
  size_t off = 0;
  int*      cursor = (int*)(ws + off);         off = al16(off + (size_t)N * 4);
  unsigned* pairw  = (unsigned*)(ws + off);    off = al16(off + (size_t)N * CAP * 4);
  float*    pdot   = (float*)(ws + off);       off = al16(off + (size_t)2 * N * 4);
  __half*   bufH   = (__half*)(ws + off);      off = al16(off + (size_t)N * 256 * 2);
  __half*   h1f    = (__half*)(ws + off);      off = al16(off + (size_t)N * 256 * 2);
  unsigned short* W1h = (unsigned short*)(ws + off); off = al16(off + (size_t)K1 * 256 * 2);
  unsigned short* W1l = (unsigned short*)(ws + off); off = al16(off + (size_t)K1 * 256 * 2);
  unsigned short* W2h = (unsigned short*)(ws + off); off = al16(off + (size_t)256 * 256 * 2);
  unsigned short* W2l = (unsigned short*)(ws + off); off = al16(off + (size_t)256 * 256 * 2);

  const int nb_N = (N + TPB - 1) / TPB;
  const int nb_E = (E + TPB - 1) / TPB;
  const int nb_g = ((N + 3) / 4) * 2;          // 4 nodes/block x 2 chunks
  const int nb_M = (N + 63) / 64;              // GEMM row blocks
  const int nb_W = ((K1 + 256) * 256 + TPB - 1) / TPB;

  // CSR build (col<<16 | fp16 coef) + weight packing
  k_zero_i32<<<nb_N, TPB, 0, stream>>>(cursor, N);
  k_scatter<<<nb_E, TPB, 0, stream>>>(srcp, dstp, cursor, pairw, E);
  k_coef<<<(N * 64 + TPB - 1) / TPB, TPB, 0, stream>>>(cursor, pairw, N);
  k_packW<<<nb_W, TPB, 0, stream>>>(W1, W1h, W1l, K1, W2, W2h, W2l, 256);

  // layer 1
  k_gemm1<<<nb_M, TPB, 0, stream>>>(x, W1h, W1l, bufH, N, K1);
  k_gather1<<<nb_g, TPB, 0, stream>>>((const __half2*)bufH, cursor, pairw, b1,
                                      (__half2*)h1f, N);

  // layer 2 (+ fused pooling partials)
  k_gemm2<<<nb_M, TPB, 0, stream>>>(h1f, W2h, W2l, bufH, N, 256);
  k_gather2<<<nb_g, TPB, 0, stream>>>((const __half2*)bufH, cursor, pairw, b2,
                                      wfc, pdot, N);

  // pooling + fc, one block per group, no atomics
  k_pool<<<G, TPB, 0, stream>>>(pdot, batch, bfc, out, N);
}

// Round 12
// 211.399 us; speedup vs baseline: 2.7048x; 2.7048x over previous
//
#include <hip/hip_runtime.h>
#include <hip/hip_fp16.h>

// DeepfakeGNN: 2-layer GCN (self-loops, symmetric norm) + mean-pool + linear.
// Round 11 -> 12: R11 instrumentation showed gemm1 = 28.4us/rep with
// Occupancy 12.8% (313 blocks / 256 CUs = 1.2 waves/SIMD), MfmaUtil 22%,
// HBM 1.1 TB/s (latency-bound cold A-read). Fix: 64x128 tiles -> 626 blocks
// (2-3 blocks/CU co-resident) + raw-prefetch pipeline (next k-block's global
// loads issued before current MFMA section). Everything else = R10.

#define TPB 256
#define CAP 64  // slots per node; max degree ~40 for this input

typedef short bfrag __attribute__((ext_vector_type(8)));   // 8 bf16 (4 VGPRs)
typedef float f32x4 __attribute__((ext_vector_type(4)));   // MFMA acc

__device__ __forceinline__ unsigned short f2bf(float f) {
  unsigned u = __float_as_uint(f);
  unsigned r = u + 0x7FFFu + ((u >> 16) & 1u);  // RNE
  return (unsigned short)(r >> 16);
}
__device__ __forceinline__ float bf2f(unsigned short b) {
  return __uint_as_float(((unsigned)b) << 16);
}

__global__ __launch_bounds__(TPB) void k_zero_i32(int* p, int n) {
  int i = blockIdx.x * TPB + threadIdx.x;
  if (i < n) p[i] = 0;
}

// pairw[d*CAP + slot] = src<<16 ; cursor[d] ends = in-degree (excl self loop)
__global__ __launch_bounds__(TPB) void k_scatter(const int* __restrict__ src,
                                                 const int* __restrict__ dst,
                                                 int* __restrict__ cursor,
                                                 unsigned* __restrict__ pairw, int E) {
  int e = blockIdx.x * TPB + threadIdx.x;
  if (e >= E) return;
  int s = src[e], d = dst[e];
  int pos = d * CAP + atomicAdd(&cursor[d], 1);
  pairw[pos] = ((unsigned)s) << 16;
}

// OR fp16(dinv[src]*dinv[dst]) into low 16 bits; dinv = rsqrt(cnt+1) on the fly
__global__ __launch_bounds__(TPB) void k_coef(const int* __restrict__ cnt,
                                              unsigned* __restrict__ pairw, int N) {
  int t = blockIdx.x * TPB + threadIdx.x;
  int node = t >> 6;
  if (node >= N) return;
  int slot = t & 63;
  if (slot >= cnt[node]) return;
  int pos = node * CAP + slot;
  unsigned u = pairw[pos];
  int j = (int)(u >> 16);
  float di = rsqrtf((float)(cnt[node] + 1));
  float dj = rsqrtf((float)(cnt[j] + 1));
  __half h = __float2half(di * dj);
  pairw[pos] = u | (unsigned)(*(unsigned short*)&h);
}

// pack W1 and W2 fp32 -> split bf16 fragment layout [K/32][256][32], one launch
__global__ __launch_bounds__(TPB) void k_packW(const float* __restrict__ W1,
                                               unsigned short* __restrict__ B1h,
                                               unsigned short* __restrict__ B1l,
                                               int K1,
                                               const float* __restrict__ W2,
                                               unsigned short* __restrict__ B2h,
                                               unsigned short* __restrict__ B2l,
                                               int K2) {
  int t = blockIdx.x * TPB + threadIdx.x;
  const float* W = W1;
  unsigned short* Bh = B1h;
  unsigned short* Bl = B1l;
  if (t >= K1 * 256) {
    t -= K1 * 256;
    if (t >= K2 * 256) return;
    W = W2; Bh = B2h; Bl = B2l;
  }
  int n = t & 255, k = t >> 8;
  float v = W[(size_t)k * 256 + n];
  unsigned short h = f2bf(v);
  unsigned short l = f2bf(v - bf2f(h));
  size_t o = ((size_t)(k >> 5) * 256 + n) * 32 + (k & 31);
  Bh[o] = h;
  Bl[o] = l;
}

// ---------- split-bf16 MFMA GEMM, C[M,256] = A[M,K] @ W[K,256], C in fp16 ----
// 256 thr = 4 waves; tile 64 rows x 128 cols (grid.x = 2 col-blocks -> 626
// blocks, 2-3 co-resident/CU); BK=64 per barrier pair; raw-prefetch pipeline.
#define LDSTR 72  // 64 + 8 pad

__device__ __forceinline__ void gemm_core(const unsigned short* __restrict__ Bph,
                                          const unsigned short* __restrict__ Bpl,
                                          __half* __restrict__ C, int M, int K,
                                          int bm, int bn,
                                          unsigned short (*AsH)[LDSTR],
                                          unsigned short (*AsL)[LDSTR],
                                          const float* A_f32,
                                          const __half* A_f16) {
  const int tid = threadIdx.x;
  const int w = tid >> 6;
  const int lane = tid & 63;
  const int q = lane >> 4;        // quad 0..3
  const int nin = lane & 15;
  const int r  = tid >> 2;        // 0..63  staging row
  const int cb = (tid & 3) << 4;  // 0,16,32,48 staging k-offset (16 elems/thr)
  const int row = bm + r;
  const bool rok = row < M;

  size_t bbase[2];
#pragma unroll
  for (int nt = 0; nt < 2; ++nt)
    bbase[nt] = ((size_t)(bn + w * 32 + nt * 16 + nin)) * 32 + q * 8;

  f32x4 acc[4][2];
#pragma unroll
  for (int mt = 0; mt < 4; ++mt)
#pragma unroll
    for (int nt = 0; nt < 2; ++nt) acc[mt][nt] = (f32x4){0.f, 0.f, 0.f, 0.f};

  // raw prefetch buffers (convert deferred to LDS-write time)
  float4 rf[4];
  uint4  rh[2];
  if (A_f32) {
    rf[0] = make_float4(0.f, 0.f, 0.f, 0.f); rf[1] = rf[0]; rf[2] = rf[0]; rf[3] = rf[0];
    if (rok) {
      const float* Ap = A_f32 + (size_t)row * K + cb;
      rf[0] = *(const float4*)(Ap);
      rf[1] = *(const float4*)(Ap + 4);
      rf[2] = *(const float4*)(Ap + 8);
      rf[3] = *(const float4*)(Ap + 12);
    }
  } else {
    rh[0] = make_uint4(0, 0, 0, 0); rh[1] = rh[0];
    if (rok) {
      const __half* Ap = A_f16 + (size_t)row * K + cb;
      rh[0] = *(const uint4*)(Ap);
      rh[1] = *(const uint4*)(Ap + 8);
    }
  }

  for (int kb = 0; kb < K; kb += 64) {
    // convert prefetched raw -> split bf16
    float vv[16];
    if (A_f32) {
      *(float4*)&vv[0] = rf[0]; *(float4*)&vv[4] = rf[1];
      *(float4*)&vv[8] = rf[2]; *(float4*)&vv[12] = rf[3];
    } else {
      __half hh[16];
      *(uint4*)&hh[0] = rh[0]; *(uint4*)&hh[8] = rh[1];
#pragma unroll
      for (int j = 0; j < 16; ++j) vv[j] = __half2float(hh[j]);
    }
    unsigned short h16[16], l16[16];
#pragma unroll
    for (int j = 0; j < 16; ++j) {
      h16[j] = f2bf(vv[j]);
      l16[j] = f2bf(vv[j] - bf2f(h16[j]));   // exact for fp16 inputs
    }
    __syncthreads();
    *(uint4*)&AsH[r][cb]     = *(uint4*)&h16[0];
    *(uint4*)&AsH[r][cb + 8] = *(uint4*)&h16[8];
    *(uint4*)&AsL[r][cb]     = *(uint4*)&l16[0];
    *(uint4*)&AsL[r][cb + 8] = *(uint4*)&l16[8];
    __syncthreads();

    // issue next k-block's global loads NOW (fly under the MFMA section)
    int kn = kb + 64;
    if (kn < K) {
      if (A_f32) {
        if (rok) {
          const float* Ap = A_f32 + (size_t)row * K + kn + cb;
          rf[0] = *(const float4*)(Ap);
          rf[1] = *(const float4*)(Ap + 4);
          rf[2] = *(const float4*)(Ap + 8);
          rf[3] = *(const float4*)(Ap + 12);
        }
      } else {
        if (rok) {
          const __half* Ap = A_f16 + (size_t)row * K + kn + cb;
          rh[0] = *(const uint4*)(Ap);
          rh[1] = *(const uint4*)(Ap + 8);
        }
      }
    }

#pragma unroll
    for (int s = 0; s < 2; ++s) {
      const size_t koff = (size_t)((kb >> 5) + s) * 256 * 32;
      bfrag bh[2], bl[2];
#pragma unroll
      for (int nt = 0; nt < 2; ++nt) {
        bh[nt] = *(const bfrag*)(Bph + koff + bbase[nt]);
        bl[nt] = *(const bfrag*)(Bpl + koff + bbase[nt]);
      }
      bfrag ah[4], al[4];
#pragma unroll
      for (int mt = 0; mt < 4; ++mt) {
        ah[mt] = *(const bfrag*)&AsH[mt * 16 + nin][s * 32 + q * 8];
        al[mt] = *(const bfrag*)&AsL[mt * 16 + nin][s * 32 + q * 8];
      }
#pragma unroll
      for (int mt = 0; mt < 4; ++mt)
#pragma unroll
        for (int nt = 0; nt < 2; ++nt) {
          acc[mt][nt] = __builtin_amdgcn_mfma_f32_16x16x32_bf16(ah[mt], bh[nt], acc[mt][nt], 0, 0, 0);
          acc[mt][nt] = __builtin_amdgcn_mfma_f32_16x16x32_bf16(ah[mt], bl[nt], acc[mt][nt], 0, 0, 0);
          acc[mt][nt] = __builtin_amdgcn_mfma_f32_16x16x32_bf16(al[mt], bh[nt], acc[mt][nt], 0, 0, 0);
        }
    }
  }

  // C/D layout: col = lane&15, row = quad*4 + reg ; store fp16
#pragma unroll
  for (int mt = 0; mt < 4; ++mt) {
    int rb = bm + mt * 16 + q * 4;
#pragma unroll
    for (int reg = 0; reg < 4; ++reg) {
      int rr = rb + reg;
      if (rr < M) {
#pragma unroll
        for (int nt = 0; nt < 2; ++nt)
          C[(size_t)rr * 256 + bn + w * 32 + nt * 16 + nin] = __float2half(acc[mt][nt][reg]);
      }
    }
  }
}

__global__ __launch_bounds__(TPB) void k_gemm1(const float* __restrict__ A,
                                               const unsigned short* __restrict__ Bph,
                                               const unsigned short* __restrict__ Bpl,
                                               __half* __restrict__ C, int M, int K) {
  __shared__ unsigned short AsH[64][LDSTR];
  __shared__ unsigned short AsL[64][LDSTR];
  gemm_core(Bph, Bpl, C, M, K, blockIdx.y * 64, blockIdx.x * 128, AsH, AsL, A, nullptr);
}

__global__ __launch_bounds__(TPB) void k_gemm2(const __half* __restrict__ A,
                                               const unsigned short* __restrict__ Bph,
                                               const unsigned short* __restrict__ Bpl,
                                               __half* __restrict__ C, int M, int K) {
  __shared__ unsigned short AsH[64][LDSTR];
  __shared__ unsigned short AsL[64][LDSTR];
  gemm_core(Bph, Bpl, C, M, K, blockIdx.y * 64, blockIdx.x * 128, AsH, AsL, nullptr, A);
}

// ---------- chunked gathers: 2 chunks x 128 cols; chunk = blockIdx&1 ----------
__device__ __forceinline__ float2 gather_row2(const __half2* __restrict__ xh2,
                                              const unsigned* __restrict__ pairw,
                                              int node, int deg, int c2) {
  float ax = 0.f, ay = 0.f;
  int base = node * CAP;
  int k = 0;
  for (; k + 7 < deg; k += 8) {
#pragma unroll
    for (int u = 0; u < 8; ++u) {
      unsigned uu = pairw[base + k + u];
      const __half2* rp = xh2 + ((size_t)(uu >> 16) << 7);  // row*128 half2
      unsigned short cb16 = (unsigned short)(uu & 0xFFFFu);
      float coef = __half2float(*(__half*)&cb16);
      float2 v = __half22float2(rp[c2]);
      ax = fmaf(coef, v.x, ax);
      ay = fmaf(coef, v.y, ay);
    }
  }
  for (; k < deg; ++k) {
    unsigned uu = pairw[base + k];
    const __half2* rp = xh2 + ((size_t)(uu >> 16) << 7);
    unsigned short cb16 = (unsigned short)(uu & 0xFFFFu);
    float coef = __half2float(*(__half*)&cb16);
    float2 v = __half22float2(rp[c2]);
    ax = fmaf(coef, v.x, ax);
    ay = fmaf(coef, v.y, ay);
  }
  return make_float2(ax, ay);
}

// layer 1: h1 = relu(agg + b1), stored fp16 (half2 store)
__global__ __launch_bounds__(TPB) void k_gather1(const __half2* __restrict__ xh2,
                                                 const int* __restrict__ cnt,
                                                 const unsigned* __restrict__ pairw,
                                                 const float* __restrict__ bias,
                                                 __half2* __restrict__ h1,
                                                 int N) {
  int b = blockIdx.x;
  int chunk = b & 1;
  int node = __builtin_amdgcn_readfirstlane((b >> 1) * 4 + (threadIdx.x >> 6));
  if (node >= N) return;
  int deg = __builtin_amdgcn_readfirstlane(cnt[node]);
  int c2 = chunk * 64 + (threadIdx.x & 63);    // half2 index within row
  float2 acc = gather_row2(xh2, pairw, node, deg, c2);
  float di2 = 1.f / (float)(deg + 1);          // dinv^2 exactly
  float2 sv = __half22float2(xh2[(size_t)node * 128 + c2]);
  acc.x = fmaf(di2, sv.x, acc.x);
  acc.y = fmaf(di2, sv.y, acc.y);
  const float2 bb = *(const float2*)&bias[2 * c2];
  acc.x = fmaxf(acc.x + bb.x, 0.f);
  acc.y = fmaxf(acc.y + bb.y, 0.f);
  h1[(size_t)node * 128 + c2] = __floats2half2_rn(acc.x, acc.y);
}

// layer 2 + pooling partial: pdot[chunk][node] = sum_c relu(agg+b2)[c]*wfc[c]
__global__ __launch_bounds__(TPB) void k_gather2(const __half2* __restrict__ xh2,
                                                 const int* __restrict__ cnt,
                                                 const unsigned* __restrict__ pairw,
                                                 const float* __restrict__ bias,
                                                 const float* __restrict__ wfc,
                                                 float* __restrict__ pdot, int N) {
  int b = blockIdx.x;
  int chunk = b & 1;
  int node = __builtin_amdgcn_readfirstlane((b >> 1) * 4 + (threadIdx.x >> 6));
  if (node >= N) return;
  int deg = __builtin_amdgcn_readfirstlane(cnt[node]);
  int lane = threadIdx.x & 63;
  int c2 = chunk * 64 + lane;
  float2 acc = gather_row2(xh2, pairw, node, deg, c2);
  float di2 = 1.f / (float)(deg + 1);
  float2 sv = __half22float2(xh2[(size_t)node * 128 + c2]);
  acc.x = fmaf(di2, sv.x, acc.x);
  acc.y = fmaf(di2, sv.y, acc.y);
  const float2 bb = *(const float2*)&bias[2 * c2];
  const float2 ff = *(const float2*)&wfc[2 * c2];
  float s = fmaxf(acc.x + bb.x, 0.f) * ff.x + fmaxf(acc.y + bb.y, 0.f) * ff.y;
#pragma unroll
  for (int off = 32; off > 0; off >>= 1) s += __shfl_down(s, off);
  if (lane == 0) pdot[(size_t)chunk * N + node] = s;
}

// one block per group: binary-search [start,end) in sorted batch, reduce pdot.
__global__ __launch_bounds__(TPB) void k_pool(const float* __restrict__ pdot,
                                              const int* __restrict__ batch,
                                              const float* __restrict__ bfc,
                                              float* __restrict__ out, int N) {
  int g = blockIdx.x;
  int lo = 0, hi = N;
  while (lo < hi) { int mid = (lo + hi) >> 1; if (batch[mid] < g) lo = mid + 1; else hi = mid; }
  int start = lo;
  hi = N;
  while (lo < hi) { int mid = (lo + hi) >> 1; if (batch[mid] < g + 1) lo = mid + 1; else hi = mid; }
  int end = lo;

  float s = 0.f;
  for (int i = start + threadIdx.x; i < end; i += TPB)
    s += pdot[i] + pdot[(size_t)N + i];
  __shared__ float red[4];
  int lane = threadIdx.x & 63, wave = threadIdx.x >> 6;
#pragma unroll
  for (int off = 32; off > 0; off >>= 1) s += __shfl_down(s, off);
  if (lane == 0) red[wave] = s;
  __syncthreads();
  if (threadIdx.x == 0) {
    float tot = red[0] + red[1] + red[2] + red[3];
    float c = (float)(end - start);
    out[g] = tot / fmaxf(c, 1.f) + bfc[0];
  }
}

extern "C" void kernel_launch(void* const* d_in, const int* in_sizes, int n_in,
                              void* d_out, int out_size, void* d_ws, size_t ws_size,
                              hipStream_t stream) {
  const float* x    = (const float*)d_in[0];
  const int*   eidx = (const int*)d_in[1];
  const int*   batch= (const int*)d_in[2];
  const float* W1   = (const float*)d_in[3];
  const float* b1   = (const float*)d_in[4];
  const float* W2   = (const float*)d_in[5];
  const float* b2   = (const float*)d_in[6];
  const float* wfc  = (const float*)d_in[7];
  const float* bfc  = (const float*)d_in[8];
  float* out = (float*)d_out;

  const int N  = in_sizes[2];        // 20000
  const int E  = in_sizes[1] / 2;    // 320000
  const int K1 = in_sizes[0] / N;    // 512
  const int G  = out_size;           // 128

  const int* srcp = eidx;
  const int* dstp = eidx + E;

  auto al16 = [](size_t v) { return (v + 15) & ~(size_t)15; };
  char* ws = (char*)d_ws;
  size_t off = 0;
  int*      cursor = (int*)(ws + off);         off = al16(off + (size_t)N * 4);
  unsigned* pairw  = (unsigned*)(ws + off);    off = al16(off + (size_t)N * CAP * 4);
  float*    pdot   = (float*)(ws + off);       off = al16(off + (size_t)2 * N * 4);
  __half*   bufH   = (__half*)(ws + off);      off = al16(off + (size_t)N * 256 * 2);
  __half*   h1f    = (__half*)(ws + off);      off = al16(off + (size_t)N * 256 * 2);
  unsigned short* W1h = (unsigned short*)(ws + off); off = al16(off + (size_t)K1 * 256 * 2);
  unsigned short* W1l = (unsigned short*)(ws + off); off = al16(off + (size_t)K1 * 256 * 2);
  unsigned short* W2h = (unsigned short*)(ws + off); off = al16(off + (size_t)256 * 256 * 2);
  unsigned short* W2l = (unsigned short*)(ws + off); off = al16(off + (size_t)256 * 256 * 2);

  const int nb_N = (N + TPB - 1) / TPB;
  const int nb_E = (E + TPB - 1) / TPB;
  const int nb_g = ((N + 3) / 4) * 2;          // 4 nodes/block x 2 chunks
  const dim3 nb_G(2, (N + 63) / 64);           // GEMM: 2 col-blocks x row-blocks
  const int nb_W = ((K1 + 256) * 256 + TPB - 1) / TPB;

  // CSR build (col<<16 | fp16 coef) + weight packing
  k_zero_i32<<<nb_N, TPB, 0, stream>>>(cursor, N);
  k_scatter<<<nb_E, TPB, 0, stream>>>(srcp, dstp, cursor, pairw, E);
  k_coef<<<(N * 64 + TPB - 1) / TPB, TPB, 0, stream>>>(cursor, pairw, N);
  k_packW<<<nb_W, TPB, 0, stream>>>(W1, W1h, W1l, K1, W2, W2h, W2l, 256);

  // layer 1
  k_gemm1<<<nb_G, TPB, 0, stream>>>(x, W1h, W1l, bufH, N, K1);
  k_gather1<<<nb_g, TPB, 0, stream>>>((const __half2*)bufH, cursor, pairw, b1,
                                      (__half2*)h1f, N);

  // layer 2 (+ fused pooling partials)
  k_gemm2<<<nb_G, TPB, 0, stream>>>(h1f, W2h, W2l, bufH, N, 256);
  k_gather2<<<nb_g, TPB, 0, stream>>>((const __half2*)bufH, cursor, pairw, b2,
                                      wfc, pdot, N);

  // pooling + fc, one block per group, no atomics
  k_pool<<<G, TPB, 0, stream>>>(pdot, batch, bfc, out, N);
}